// Round 14
// baseline (240.632 us; speedup 1.0000x reference)
//
#include <hip/hip_runtime.h>
#include <hip/hip_bf16.h>
#include <math.h>

#define NV 64
#define ND 64
#define NTOK 8192
#define LN_EPS 1e-5f
#define SROW 4160                // stb row stride in shorts (8320 B)
#define WROW 4160                // wct row stride in shorts

typedef __attribute__((ext_vector_type(8))) short s8v;    // 8 bf16 = 4 VGPR
typedef __attribute__((ext_vector_type(4))) float f4v;    // MFMA C/D
typedef __attribute__((ext_vector_type(4))) int   i4v;

__device__ __forceinline__ float sigm_f(float x) { return 1.f / (1.f + __expf(-x)); }
__device__ __forceinline__ float elu_f(float x)  { return x > 0.f ? x : (__expf(x) - 1.f); }

__device__ __forceinline__ float bf16_to_f(unsigned short s) {
    union { unsigned int u; float f; } c; c.u = ((unsigned int)s) << 16;
    return c.f;
}
__device__ __forceinline__ unsigned short bf16_rn(float f) {
    union { float f; unsigned int u; } c; c.f = f;
    return (unsigned short)((c.u + 0x8000u) >> 16);
}

// ---------------- Prepack: weight transposes via LDS tiles (coalesced R+W)
__global__ __launch_bounds__(256) void vsn_prepack(
    const float* __restrict__ W2, const float* __restrict__ Wg,
    const float* __restrict__ Wn1, const float* __restrict__ Wns,
    short* __restrict__ w2b, short* __restrict__ wgb,
    short* __restrict__ wct)
{
    __shared__ float T[64][65];
    const int b = blockIdx.x, t = threadIdx.x;

    if (b < 64) {
        const float* src = W2 + (size_t)b * 4096;
        short* dst = w2b + (size_t)b * 4096;
        #pragma unroll
        for (int pass = 0; pass < 2; ++pass) {
            #pragma unroll
            for (int i = 0; i < 16; ++i) {
                int id = i * 256 + t;
                T[id & 63][id >> 6] = src[id];
            }
            __syncthreads();
            #pragma unroll
            for (int i = 0; i < 16; ++i) {
                int id = i * 256 + t;
                dst[id] = (short)bf16_rn(T[id >> 6][id & 63]);
            }
            __syncthreads();
            src = Wg + (size_t)b * 4096;
            dst = wgb + (size_t)b * 4096;
        }
    } else {
        int tb = b - 64;
        int half = tb >> 6, kt = tb & 63;
        const float* src = (half == 0 ? Wn1 : Wns) + (size_t)(kt * 64) * 64;
        #pragma unroll
        for (int i = 0; i < 16; ++i) {
            int id = i * 256 + t;
            T[id & 63][id >> 6] = src[id];
        }
        __syncthreads();
        #pragma unroll
        for (int i = 0; i < 16; ++i) {
            int id = i * 256 + t;
            int n = id >> 6, r = id & 63;
            wct[(size_t)(half * 64 + n) * WROW + kt * 64 + r] = (short)bf16_rn(T[n][r]);
        }
    }
}

// ---------------- Stage 1: per-variable GRN + LN via bf16 MFMA -> stacked bf16
// [R13 verified @60us] grid (64 x 16); block loops 4 token-tiles, weights hoisted.
__global__ __launch_bounds__(256) void vsn_stage1(
    const float* __restrict__ x,
    const float* __restrict__ W1, const float* __restrict__ b1,
    const short* __restrict__ w2b, const short* __restrict__ wgb,
    const float* __restrict__ b2, const float* __restrict__ bg,
    const float* __restrict__ Wsk, const float* __restrict__ bsk,
    const float* __restrict__ gamma, const float* __restrict__ beta,
    unsigned short* __restrict__ stb)
{
    const int t = threadIdx.x;
    const int wave = t >> 6, lane = t & 63;
    const int m16 = lane & 15, quad = lane >> 4;
    const int v = blockIdx.y * 4 + wave;

    __shared__ float xs[4][32];
    __shared__ __align__(16) unsigned short h2s[4][32][72];

    float w1k[2][8], b1k[2][8];
    #pragma unroll
    for (int kt = 0; kt < 2; ++kt) {
        *(float4*)&w1k[kt][0] = *(const float4*)(W1 + v * 64 + kt * 32 + quad * 8);
        *(float4*)&w1k[kt][4] = *(const float4*)(W1 + v * 64 + kt * 32 + quad * 8 + 4);
        *(float4*)&b1k[kt][0] = *(const float4*)(b1 + v * 64 + kt * 32 + quad * 8);
        *(float4*)&b1k[kt][4] = *(const float4*)(b1 + v * 64 + kt * 32 + quad * 8 + 4);
    }
    float b2d[4], bgd[4], wskd[4], bskd[4], gamd[4], betd[4];
    #pragma unroll
    for (int ni = 0; ni < 4; ++ni) {
        int d = v * 64 + ni * 16 + m16;
        b2d[ni] = b2[d]; bgd[ni] = bg[d]; wskd[ni] = Wsk[d]; bskd[ni] = bsk[d];
        gamd[ni] = gamma[d]; betd[ni] = beta[d];
    }
    const size_t wb = (size_t)v * 4096;

    for (int tt4 = 0; tt4 < 4; ++tt4) {
        const int tile0 = blockIdx.x * 128 + tt4 * 32;

        if (lane < 32) xs[wave][lane] = x[(size_t)(tile0 + lane) * NV + v];

        s8v a[2][2];
        #pragma unroll
        for (int kt = 0; kt < 2; ++kt)
            #pragma unroll
            for (int mi = 0; mi < 2; ++mi) {
                float xv = xs[wave][mi * 16 + m16];
                float h[8];
                #pragma unroll
                for (int j = 0; j < 8; ++j) h[j] = elu_f(fmaf(xv, w1k[kt][j], b1k[kt][j]));
                i4v av;
                #pragma unroll
                for (int p = 0; p < 4; ++p) {
                    unsigned int u0 = __float_as_uint(h[2 * p]);
                    unsigned int u1 = __float_as_uint(h[2 * p + 1]);
                    av[p] = (int)((u1 & 0xffff0000u) | (u0 >> 16));
                }
                a[mi][kt] = *(s8v*)&av;
            }

        f4v hacc[2][4];
        #pragma unroll
        for (int mi = 0; mi < 2; ++mi)
            #pragma unroll
            for (int ni = 0; ni < 4; ++ni) hacc[mi][ni] = (f4v){0.f, 0.f, 0.f, 0.f};
        #pragma unroll
        for (int ni = 0; ni < 4; ++ni)
            #pragma unroll
            for (int kt = 0; kt < 2; ++kt) {
                s8v bh = *(const s8v*)(w2b + wb + (size_t)(ni * 16 + m16) * 64 + kt * 32 + quad * 8);
                #pragma unroll
                for (int mi = 0; mi < 2; ++mi)
                    hacc[mi][ni] = __builtin_amdgcn_mfma_f32_16x16x32_bf16(a[mi][kt], bh, hacc[mi][ni], 0, 0, 0);
            }
        #pragma unroll
        for (int mi = 0; mi < 2; ++mi)
            #pragma unroll
            for (int ni = 0; ni < 4; ++ni)
                #pragma unroll
                for (int r = 0; r < 4; ++r) hacc[mi][ni][r] += b2d[ni];

        #pragma unroll
        for (int mi = 0; mi < 2; ++mi)
            #pragma unroll
            for (int ni = 0; ni < 4; ++ni)
                #pragma unroll
                for (int r = 0; r < 4; ++r)
                    h2s[wave][mi * 16 + quad * 4 + r][ni * 16 + m16] =
                        (unsigned short)(__float_as_uint(hacc[mi][ni][r]) >> 16);

        s8v c[2][2];
        #pragma unroll
        for (int mi = 0; mi < 2; ++mi)
            #pragma unroll
            for (int kt = 0; kt < 2; ++kt)
                c[mi][kt] = *(const s8v*)&h2s[wave][mi * 16 + m16][kt * 32 + quad * 8];

        f4v gacc[2][4];
        #pragma unroll
        for (int mi = 0; mi < 2; ++mi)
            #pragma unroll
            for (int ni = 0; ni < 4; ++ni) gacc[mi][ni] = (f4v){0.f, 0.f, 0.f, 0.f};
        #pragma unroll
        for (int ni = 0; ni < 4; ++ni)
            #pragma unroll
            for (int kt = 0; kt < 2; ++kt) {
                s8v bh = *(const s8v*)(wgb + wb + (size_t)(ni * 16 + m16) * 64 + kt * 32 + quad * 8);
                #pragma unroll
                for (int mi = 0; mi < 2; ++mi)
                    gacc[mi][ni] = __builtin_amdgcn_mfma_f32_16x16x32_bf16(c[mi][kt], bh, gacc[mi][ni], 0, 0, 0);
            }

        {
            float xtok[2][4];
            #pragma unroll
            for (int mi = 0; mi < 2; ++mi)
                #pragma unroll
                for (int r = 0; r < 4; ++r) xtok[mi][r] = xs[wave][mi * 16 + quad * 4 + r];
            #pragma unroll
            for (int mi = 0; mi < 2; ++mi)
                #pragma unroll
                for (int ni = 0; ni < 4; ++ni)
                    #pragma unroll
                    for (int r = 0; r < 4; ++r) {
                        float g = sigm_f(gacc[mi][ni][r] + bgd[ni]);
                        gacc[mi][ni][r] = fmaf(xtok[mi][r], wskd[ni], bskd[ni]) + g * hacc[mi][ni][r];
                    }
        }

        #pragma unroll
        for (int mi = 0; mi < 2; ++mi)
            #pragma unroll
            for (int r = 0; r < 4; ++r) {
                float s0 = gacc[mi][0][r], s1 = gacc[mi][1][r], s2 = gacc[mi][2][r], s3 = gacc[mi][3][r];
                float sum = s0 + s1 + s2 + s3;
                float sq  = s0 * s0 + s1 * s1 + s2 * s2 + s3 * s3;
                #pragma unroll
                for (int m = 1; m < 16; m <<= 1) { sum += __shfl_xor(sum, m); sq += __shfl_xor(sq, m); }
                float mu  = sum * 0.015625f;
                float var = sq * 0.015625f - mu * mu;
                float rs  = rsqrtf(var + LN_EPS);
                size_t base = (size_t)(tile0 + mi * 16 + quad * 4 + r) * SROW + (size_t)v * 64 + m16;
                #pragma unroll
                for (int ni = 0; ni < 4; ++ni)
                    stb[base + ni * 16] =
                        bf16_rn((gacc[mi][ni][r] - mu) * rs * gamd[ni] + betd[ni]);
            }
    }
}

// ---------------- Fused Stage 2 v3: 256 blocks x 1024 threads (16 waves), 32 tok.
// Wave w: kq = w>>2 (K-quarter 1024), mtile = w&1 (16 tok), nh = (w>>1)&1 (64 n).
// kq>=1 publish partials to 3 LDS buffers; kq0 accumulates; tail GRN/LN/softmax
// + weighted sum inline (stb rows L2-warm from the K-loop). No part[] round-trip.
__global__ __launch_bounds__(1024) void vsn_stage2(
    const unsigned short* __restrict__ stb,   // [8192][SROW]
    const short* __restrict__ wct,            // [128][WROW]
    const float* __restrict__ bn1,
    const float* __restrict__ Wn2, const float* __restrict__ bn2,
    const float* __restrict__ Wng, const float* __restrict__ bng,
    const float* __restrict__ bns,
    const float* __restrict__ ngamma, const float* __restrict__ nbeta,
    float* __restrict__ out)
{
    const int t = threadIdx.x;
    const int wave = t >> 6, lane = t & 63;
    const int m16 = lane & 15, quad = lane >> 4;
    const int kq = wave >> 2;
    const int mtile = wave & 1, nh = (wave >> 1) & 1;
    const int tok0 = blockIdx.x * 32;

    __shared__ __align__(16) float P[3][32][132];   // 50688 B
    float (*S)[132] = P[0];                          // overlays buffer 0 after reads
    float* base1 = &P[1][0][0];
    float (*hw1)[64] = (float(*)[64])base1;
    float (*skw)[64] = (float(*)[64])(base1 + 2048);
    float (*hw2)[64] = (float(*)[64])(&P[2][0][0]);
    float (*s2m)[64] = hw1;   // hw1 dead when s2 written
    float (*wgt)[64] = skw;   // skw dead when wgt written

    const short* A = (const short*)stb;
    const int k0 = kq * 1024;

    // ---- K-loop: this wave's quarter; 16-token x 64-col tile
    f4v acc[4];
    #pragma unroll
    for (int nj = 0; nj < 4; ++nj) acc[nj] = (f4v){0.f, 0.f, 0.f, 0.f};

    const short* arow = A + (size_t)(tok0 + mtile * 16 + m16) * SROW + k0 + quad * 8;
    const short* brow = wct + (size_t)(nh * 64 + m16) * WROW + k0 + quad * 8;

    #pragma unroll 4
    for (int kk = 0; kk < 1024; kk += 32) {
        s8v a0 = *(const s8v*)(arow + kk);
        s8v b[4];
        #pragma unroll
        for (int nj = 0; nj < 4; ++nj)
            b[nj] = *(const s8v*)(brow + (size_t)nj * 16 * WROW + kk);
        #pragma unroll
        for (int nj = 0; nj < 4; ++nj)
            acc[nj] = __builtin_amdgcn_mfma_f32_16x16x32_bf16(a0, b[nj], acc[nj], 0, 0, 0);
    }

    // ---- reduce: kq 1..3 publish; kq 0 accumulates and writes S
    if (kq >= 1) {
        #pragma unroll
        for (int nj = 0; nj < 4; ++nj)
            #pragma unroll
            for (int r = 0; r < 4; ++r)
                P[kq - 1][mtile * 16 + quad * 4 + r][nh * 64 + nj * 16 + m16] = acc[nj][r];
    }
    __syncthreads();
    if (kq == 0) {
        #pragma unroll
        for (int nj = 0; nj < 4; ++nj)
            #pragma unroll
            for (int r = 0; r < 4; ++r) {
                int row = mtile * 16 + quad * 4 + r, col = nh * 64 + nj * 16 + m16;
                float v = acc[nj][r] + P[0][row][col] + P[1][row][col] + P[2][row][col];
                S[row][col] = v;   // S == P[0]: same thread read P[0][row][col] above
            }
    }
    __syncthreads();

    // ---- tail 1: hw1 = elu(S[:, :64]+bn1), skw = S[:, 64:]+bns
    #pragma unroll
    for (int i = 0; i < 2; ++i) {
        int idx = i * 1024 + t;
        int m = idx >> 6, j = idx & 63;
        hw1[m][j] = elu_f(S[m][j] + bn1[j]);
        skw[m][j] = S[m][64 + j] + bns[j];
    }
    __syncthreads();

    // ---- tail 2: hw2 = hw1 @ Wn2 + bn2
    #pragma unroll
    for (int i = 0; i < 2; ++i) {
        int idx = i * 1024 + t;
        int m = idx >> 6, j = idx & 63;
        float a2 = bn2[j];
        #pragma unroll
        for (int k4 = 0; k4 < 16; ++k4) {
            float4 h = *(const float4*)&hw1[m][k4 * 4];
            a2 += h.x * Wn2[(k4*4+0)*64+j] + h.y * Wn2[(k4*4+1)*64+j]
                + h.z * Wn2[(k4*4+2)*64+j] + h.w * Wn2[(k4*4+3)*64+j];
        }
        hw2[m][j] = a2;
    }
    __syncthreads();

    // ---- tail 3: gw = sigm(hw2 @ Wng + bng); s2 = skw + gw*hw2 (s2m overlays hw1)
    #pragma unroll
    for (int i = 0; i < 2; ++i) {
        int idx = i * 1024 + t;
        int m = idx >> 6, vv = idx & 63;
        float a3 = bng[vv];
        #pragma unroll
        for (int k4 = 0; k4 < 16; ++k4) {
            float4 h = *(const float4*)&hw2[m][k4 * 4];
            a3 += h.x * Wng[(k4*4+0)*64+vv] + h.y * Wng[(k4*4+1)*64+vv]
                + h.z * Wng[(k4*4+2)*64+vv] + h.w * Wng[(k4*4+3)*64+vv];
        }
        float gw = sigm_f(a3);
        s2m[m][vv] = skw[m][vv] + gw * hw2[m][vv];
    }
    __syncthreads();

    // ---- HOISTED stb loads for the weighted sum (L2-warm; independent of softmax)
    const int vloc = lane >> 3, d8 = (lane & 7) * 8;
    s8v r0[8], r1[8];
    {
        const short* s0 = A + (size_t)(tok0 + wave * 2) * SROW + d8;
        const short* s1 = s0 + SROW;
        #pragma unroll
        for (int vc = 0; vc < 8; ++vc) {
            r0[vc] = *(const s8v*)(s0 + (vc * 8 + vloc) * 64);
            r1[vc] = *(const s8v*)(s1 + (vc * 8 + vloc) * 64);
        }
    }

    // ---- tail 4: LN over v + softmax (wgt overlays skw); 32 tok x 16 lanes
    if (t < 512) {
        int tt = t >> 4, l = t & 15;
        float z[4]; float sum = 0.f, sq = 0.f;
        #pragma unroll
        for (int i = 0; i < 4; ++i) { z[i] = s2m[tt][l + 16 * i]; sum += z[i]; sq += z[i] * z[i]; }
        #pragma unroll
        for (int m = 1; m < 16; m <<= 1) { sum += __shfl_xor(sum, m); sq += __shfl_xor(sq, m); }
        float mu  = sum * 0.015625f;
        float var = sq * 0.015625f - mu * mu;
        float rs  = rsqrtf(var + LN_EPS);
        float ln[4]; float mx = -1e30f;
        #pragma unroll
        for (int i = 0; i < 4; ++i) {
            ln[i] = (z[i] - mu) * rs * ngamma[l + 16 * i] + nbeta[l + 16 * i];
            mx = fmaxf(mx, ln[i]);
        }
        #pragma unroll
        for (int m = 1; m < 16; m <<= 1) mx = fmaxf(mx, __shfl_xor(mx, m));
        float es = 0.f; float ev[4];
        #pragma unroll
        for (int i = 0; i < 4; ++i) { ev[i] = __expf(ln[i] - mx); es += ev[i]; }
        #pragma unroll
        for (int m = 1; m < 16; m <<= 1) es += __shfl_xor(es, m);
        float inv = 1.f / es;
        #pragma unroll
        for (int i = 0; i < 4; ++i) wgt[tt][l + 16 * i] = ev[i] * inv;
    }
    __syncthreads();

    // ---- tail 5: weighted sum; wave -> tokens {2w, 2w+1}
    {
        float acc0[8], acc1[8];
        #pragma unroll
        for (int j = 0; j < 8; ++j) { acc0[j] = 0.f; acc1[j] = 0.f; }
        #pragma unroll
        for (int vc = 0; vc < 8; ++vc) {
            int v = vc * 8 + vloc;
            float w0 = wgt[wave * 2][v], w1 = wgt[wave * 2 + 1][v];
            #pragma unroll
            for (int j = 0; j < 8; ++j) {
                acc0[j] = fmaf(w0, bf16_to_f((unsigned short)r0[vc][j]), acc0[j]);
                acc1[j] = fmaf(w1, bf16_to_f((unsigned short)r1[vc][j]), acc1[j]);
            }
        }
        #pragma unroll
        for (int m = 8; m <= 32; m <<= 1)
            #pragma unroll
            for (int j = 0; j < 8; ++j) {
                acc0[j] += __shfl_xor(acc0[j], m);
                acc1[j] += __shfl_xor(acc1[j], m);
            }
        if (lane < 8) {
            float* op = out + (size_t)(tok0 + wave * 2) * 64 + lane * 8;
            *(float4*)op       = make_float4(acc0[0], acc0[1], acc0[2], acc0[3]);
            *(float4*)(op + 4) = make_float4(acc0[4], acc0[5], acc0[6], acc0[7]);
            op += 64;
            *(float4*)op       = make_float4(acc1[0], acc1[1], acc1[2], acc1[3]);
            *(float4*)(op + 4) = make_float4(acc1[4], acc1[5], acc1[6], acc1[7]);
        }
    }
}

extern "C" void kernel_launch(void* const* d_in, const int* in_sizes, int n_in,
                              void* d_out, int out_size, void* d_ws, size_t ws_size,
                              hipStream_t stream) {
    const float* x     = (const float*)d_in[0];
    const float* W1    = (const float*)d_in[1];
    const float* b1    = (const float*)d_in[2];
    const float* W2    = (const float*)d_in[3];
    const float* b2    = (const float*)d_in[4];
    const float* Wg    = (const float*)d_in[5];
    const float* bg    = (const float*)d_in[6];
    const float* Wsk   = (const float*)d_in[7];
    const float* bsk   = (const float*)d_in[8];
    const float* gamma = (const float*)d_in[9];
    const float* beta  = (const float*)d_in[10];
    const float* Wn1   = (const float*)d_in[11];
    const float* bn1   = (const float*)d_in[12];
    const float* Wn2   = (const float*)d_in[13];
    const float* bn2   = (const float*)d_in[14];
    const float* Wng   = (const float*)d_in[15];
    const float* bng   = (const float*)d_in[16];
    const float* Wns   = (const float*)d_in[17];
    const float* bns   = (const float*)d_in[18];
    const float* ngam  = (const float*)d_in[19];
    const float* nbet  = (const float*)d_in[20];

    char* ws = (char*)d_ws;
    unsigned short* stb = (unsigned short*)ws;                   // 8192*4160*2 = 68.2 MB
    short* wct = (short*)(ws + (70u << 20));                     // 128*4160*2 = 1.1 MB
    short* w2b = (short*)(ws + (72u << 20));                     // 512 KiB each
    short* wgb = w2b + 262144;
    float* outp = (float*)d_out;

    vsn_prepack<<<dim3(192), 256, 0, stream>>>(W2, Wg, Wn1, Wns, w2b, wgb, wct);
    vsn_stage1<<<dim3(NTOK / 128, 16), 256, 0, stream>>>(
        x, W1, b1, w2b, wgb, b2, bg, Wsk, bsk, gamma, beta, stb);
    vsn_stage2<<<dim3(NTOK / 32), 1024, 0, stream>>>(
        stb, wct, bn1, Wn2, bn2, Wng, bng, bns, ngam, nbet, outp);
}

// Round 15
// 202.020 us; speedup vs baseline: 1.1911x; 1.1911x over previous
//
#include <hip/hip_runtime.h>
#include <hip/hip_bf16.h>
#include <math.h>

#define NV 64
#define ND 64
#define NTOK 8192
#define LN_EPS 1e-5f
#define SROW 4096
#define WROW 4096
#define KSPLIT 16
#define KR2 (4096 / KSPLIT)     // 256
#define BK 64
#define PROW2 (KSPLIT * 128)    // 2048

typedef __attribute__((ext_vector_type(8))) short s8v;    // 8 bf16 = 4 VGPR
typedef __attribute__((ext_vector_type(4))) float f4v;    // MFMA C/D
typedef __attribute__((ext_vector_type(4))) int   i4v;

__device__ __forceinline__ float sigm_f(float x) { return 1.f / (1.f + __expf(-x)); }
__device__ __forceinline__ float elu_f(float x)  { return x > 0.f ? x : (__expf(x) - 1.f); }

__device__ __forceinline__ float bf16_to_f(unsigned short s) {
    union { unsigned int u; float f; } c; c.u = ((unsigned int)s) << 16;
    return c.f;
}
__device__ __forceinline__ unsigned short bf16_rn(float f) {
    union { float f; unsigned int u; } c; c.f = f;
    return (unsigned short)((c.u + 0x8000u) >> 16);
}

// ---------------- Prepack: weight transposes via LDS tiles (coalesced R+W)
__global__ __launch_bounds__(256) void vsn_prepack(
    const float* __restrict__ W2, const float* __restrict__ Wg,
    const float* __restrict__ Wn1, const float* __restrict__ Wns,
    short* __restrict__ w2b, short* __restrict__ wgb,
    short* __restrict__ wct)
{
    __shared__ float T[64][65];
    const int b = blockIdx.x, t = threadIdx.x;

    if (b < 64) {
        const float* src = W2 + (size_t)b * 4096;
        short* dst = w2b + (size_t)b * 4096;
        #pragma unroll
        for (int pass = 0; pass < 2; ++pass) {
            #pragma unroll
            for (int i = 0; i < 16; ++i) {
                int id = i * 256 + t;
                T[id & 63][id >> 6] = src[id];
            }
            __syncthreads();
            #pragma unroll
            for (int i = 0; i < 16; ++i) {
                int id = i * 256 + t;
                dst[id] = (short)bf16_rn(T[id >> 6][id & 63]);
            }
            __syncthreads();
            src = Wg + (size_t)b * 4096;
            dst = wgb + (size_t)b * 4096;
        }
    } else {
        int tb = b - 64;
        int half = tb >> 6, kt = tb & 63;
        const float* src = (half == 0 ? Wn1 : Wns) + (size_t)(kt * 64) * 64;
        #pragma unroll
        for (int i = 0; i < 16; ++i) {
            int id = i * 256 + t;
            T[id & 63][id >> 6] = src[id];
        }
        __syncthreads();
        #pragma unroll
        for (int i = 0; i < 16; ++i) {
            int id = i * 256 + t;
            int n = id >> 6, r = id & 63;
            wct[(size_t)(half * 64 + n) * WROW + kt * 64 + r] = (short)bf16_rn(T[n][r]);
        }
    }
}

// ---------------- Stage 1: per-variable GRN + LN via bf16 MFMA -> stacked bf16
// [R13 verified @60us; stride back to 4096]
__global__ __launch_bounds__(256) void vsn_stage1(
    const float* __restrict__ x,
    const float* __restrict__ W1, const float* __restrict__ b1,
    const short* __restrict__ w2b, const short* __restrict__ wgb,
    const float* __restrict__ b2, const float* __restrict__ bg,
    const float* __restrict__ Wsk, const float* __restrict__ bsk,
    const float* __restrict__ gamma, const float* __restrict__ beta,
    unsigned short* __restrict__ stb)
{
    const int t = threadIdx.x;
    const int wave = t >> 6, lane = t & 63;
    const int m16 = lane & 15, quad = lane >> 4;
    const int v = blockIdx.y * 4 + wave;

    __shared__ float xs[4][32];
    __shared__ __align__(16) unsigned short h2s[4][32][72];

    float w1k[2][8], b1k[2][8];
    #pragma unroll
    for (int kt = 0; kt < 2; ++kt) {
        *(float4*)&w1k[kt][0] = *(const float4*)(W1 + v * 64 + kt * 32 + quad * 8);
        *(float4*)&w1k[kt][4] = *(const float4*)(W1 + v * 64 + kt * 32 + quad * 8 + 4);
        *(float4*)&b1k[kt][0] = *(const float4*)(b1 + v * 64 + kt * 32 + quad * 8);
        *(float4*)&b1k[kt][4] = *(const float4*)(b1 + v * 64 + kt * 32 + quad * 8 + 4);
    }
    float b2d[4], bgd[4], wskd[4], bskd[4], gamd[4], betd[4];
    #pragma unroll
    for (int ni = 0; ni < 4; ++ni) {
        int d = v * 64 + ni * 16 + m16;
        b2d[ni] = b2[d]; bgd[ni] = bg[d]; wskd[ni] = Wsk[d]; bskd[ni] = bsk[d];
        gamd[ni] = gamma[d]; betd[ni] = beta[d];
    }
    const size_t wb = (size_t)v * 4096;

    for (int tt4 = 0; tt4 < 4; ++tt4) {
        const int tile0 = blockIdx.x * 128 + tt4 * 32;

        if (lane < 32) xs[wave][lane] = x[(size_t)(tile0 + lane) * NV + v];

        s8v a[2][2];
        #pragma unroll
        for (int kt = 0; kt < 2; ++kt)
            #pragma unroll
            for (int mi = 0; mi < 2; ++mi) {
                float xv = xs[wave][mi * 16 + m16];
                float h[8];
                #pragma unroll
                for (int j = 0; j < 8; ++j) h[j] = elu_f(fmaf(xv, w1k[kt][j], b1k[kt][j]));
                i4v av;
                #pragma unroll
                for (int p = 0; p < 4; ++p) {
                    unsigned int u0 = __float_as_uint(h[2 * p]);
                    unsigned int u1 = __float_as_uint(h[2 * p + 1]);
                    av[p] = (int)((u1 & 0xffff0000u) | (u0 >> 16));
                }
                a[mi][kt] = *(s8v*)&av;
            }

        f4v hacc[2][4];
        #pragma unroll
        for (int mi = 0; mi < 2; ++mi)
            #pragma unroll
            for (int ni = 0; ni < 4; ++ni) hacc[mi][ni] = (f4v){0.f, 0.f, 0.f, 0.f};
        #pragma unroll
        for (int ni = 0; ni < 4; ++ni)
            #pragma unroll
            for (int kt = 0; kt < 2; ++kt) {
                s8v bh = *(const s8v*)(w2b + wb + (size_t)(ni * 16 + m16) * 64 + kt * 32 + quad * 8);
                #pragma unroll
                for (int mi = 0; mi < 2; ++mi)
                    hacc[mi][ni] = __builtin_amdgcn_mfma_f32_16x16x32_bf16(a[mi][kt], bh, hacc[mi][ni], 0, 0, 0);
            }
        #pragma unroll
        for (int mi = 0; mi < 2; ++mi)
            #pragma unroll
            for (int ni = 0; ni < 4; ++ni)
                #pragma unroll
                for (int r = 0; r < 4; ++r) hacc[mi][ni][r] += b2d[ni];

        #pragma unroll
        for (int mi = 0; mi < 2; ++mi)
            #pragma unroll
            for (int ni = 0; ni < 4; ++ni)
                #pragma unroll
                for (int r = 0; r < 4; ++r)
                    h2s[wave][mi * 16 + quad * 4 + r][ni * 16 + m16] =
                        (unsigned short)(__float_as_uint(hacc[mi][ni][r]) >> 16);

        s8v c[2][2];
        #pragma unroll
        for (int mi = 0; mi < 2; ++mi)
            #pragma unroll
            for (int kt = 0; kt < 2; ++kt)
                c[mi][kt] = *(const s8v*)&h2s[wave][mi * 16 + m16][kt * 32 + quad * 8];

        f4v gacc[2][4];
        #pragma unroll
        for (int mi = 0; mi < 2; ++mi)
            #pragma unroll
            for (int ni = 0; ni < 4; ++ni) gacc[mi][ni] = (f4v){0.f, 0.f, 0.f, 0.f};
        #pragma unroll
        for (int ni = 0; ni < 4; ++ni)
            #pragma unroll
            for (int kt = 0; kt < 2; ++kt) {
                s8v bh = *(const s8v*)(wgb + wb + (size_t)(ni * 16 + m16) * 64 + kt * 32 + quad * 8);
                #pragma unroll
                for (int mi = 0; mi < 2; ++mi)
                    gacc[mi][ni] = __builtin_amdgcn_mfma_f32_16x16x32_bf16(c[mi][kt], bh, gacc[mi][ni], 0, 0, 0);
            }

        {
            float xtok[2][4];
            #pragma unroll
            for (int mi = 0; mi < 2; ++mi)
                #pragma unroll
                for (int r = 0; r < 4; ++r) xtok[mi][r] = xs[wave][mi * 16 + quad * 4 + r];
            #pragma unroll
            for (int mi = 0; mi < 2; ++mi)
                #pragma unroll
                for (int ni = 0; ni < 4; ++ni)
                    #pragma unroll
                    for (int r = 0; r < 4; ++r) {
                        float g = sigm_f(gacc[mi][ni][r] + bgd[ni]);
                        gacc[mi][ni][r] = fmaf(xtok[mi][r], wskd[ni], bskd[ni]) + g * hacc[mi][ni][r];
                    }
        }

        #pragma unroll
        for (int mi = 0; mi < 2; ++mi)
            #pragma unroll
            for (int r = 0; r < 4; ++r) {
                float s0 = gacc[mi][0][r], s1 = gacc[mi][1][r], s2 = gacc[mi][2][r], s3 = gacc[mi][3][r];
                float sum = s0 + s1 + s2 + s3;
                float sq  = s0 * s0 + s1 * s1 + s2 * s2 + s3 * s3;
                #pragma unroll
                for (int m = 1; m < 16; m <<= 1) { sum += __shfl_xor(sum, m); sq += __shfl_xor(sq, m); }
                float mu  = sum * 0.015625f;
                float var = sq * 0.015625f - mu * mu;
                float rs  = rsqrtf(var + LN_EPS);
                size_t base = (size_t)(tile0 + mi * 16 + quad * 4 + r) * SROW + (size_t)v * 64 + m16;
                #pragma unroll
                for (int ni = 0; ni < 4; ++ni)
                    stb[base + ni * 16] =
                        bf16_rn((gacc[mi][ni][r] - mu) * rs * gamd[ni] + betd[ni]);
            }
    }
}

// ---------------- Stage 2a: LDS-tiled GEMM (m93-style). part[tok][s*128..] over K-range s.
// Block: 256 thr (4 waves), tile M=128 x N=128, BK=64, KSPLIT=16 -> grid (64,16).
// Staging: reg -> ds_write_b128 with next-chunk prefetch between barriers.
__global__ __launch_bounds__(256) void vsn_stage2a(
    const unsigned short* __restrict__ stb,   // [8192][SROW]
    const short* __restrict__ wct,            // [128][WROW]
    float* __restrict__ part)                 // [8192][PROW2]
{
    const int t = threadIdx.x;
    const int wave = t >> 6, lane = t & 63;
    const int m16 = lane & 15, quad = lane >> 4;
    const int tok0 = blockIdx.x * 128;
    const int s = blockIdx.y;
    const int k0 = s * KR2;

    __shared__ __align__(16) unsigned short Al[128][72];   // pad 72: 2-way banks (free)
    __shared__ __align__(16) unsigned short Bl[128][72];

    const int srow = t >> 3;            // 0..31
    const int scol = (t & 7) * 8;       // shorts (16B chunk)
    const short* A = (const short*)stb;

    f4v acc[2][8];
    #pragma unroll
    for (int mi = 0; mi < 2; ++mi)
        #pragma unroll
        for (int nj = 0; nj < 8; ++nj) acc[mi][nj] = (f4v){0.f, 0.f, 0.f, 0.f};

    // prefetch chunk 0
    s8v pa[4], pb[4];
    #pragma unroll
    for (int q = 0; q < 4; ++q) {
        int row = srow + q * 32;
        pa[q] = *(const s8v*)(A + (size_t)(tok0 + row) * SROW + k0 + scol);
        pb[q] = *(const s8v*)(wct + (size_t)row * WROW + k0 + scol);
    }

    for (int kc = 0; kc < KR2 / BK; ++kc) {
        if (kc > 0) __syncthreads();       // LDS free (previous compute done)
        #pragma unroll
        for (int q = 0; q < 4; ++q) {
            int row = srow + q * 32;
            *(s8v*)&Al[row][scol] = pa[q];
            *(s8v*)&Bl[row][scol] = pb[q];
        }
        __syncthreads();
        if (kc + 1 < KR2 / BK) {           // async prefetch next chunk
            int kn = k0 + (kc + 1) * BK;
            #pragma unroll
            for (int q = 0; q < 4; ++q) {
                int row = srow + q * 32;
                pa[q] = *(const s8v*)(A + (size_t)(tok0 + row) * SROW + kn + scol);
                pb[q] = *(const s8v*)(wct + (size_t)row * WROW + kn + scol);
            }
        }
        #pragma unroll
        for (int ks = 0; ks < 2; ++ks) {
            s8v af[2], bf[8];
            af[0] = *(const s8v*)&Al[wave * 32 + m16][ks * 32 + quad * 8];
            af[1] = *(const s8v*)&Al[wave * 32 + 16 + m16][ks * 32 + quad * 8];
            #pragma unroll
            for (int nj = 0; nj < 8; ++nj)
                bf[nj] = *(const s8v*)&Bl[nj * 16 + m16][ks * 32 + quad * 8];
            #pragma unroll
            for (int nj = 0; nj < 8; ++nj) {
                acc[0][nj] = __builtin_amdgcn_mfma_f32_16x16x32_bf16(af[0], bf[nj], acc[0][nj], 0, 0, 0);
                acc[1][nj] = __builtin_amdgcn_mfma_f32_16x16x32_bf16(af[1], bf[nj], acc[1][nj], 0, 0, 0);
            }
        }
    }

    #pragma unroll
    for (int mi = 0; mi < 2; ++mi)
        #pragma unroll
        for (int nj = 0; nj < 8; ++nj)
            #pragma unroll
            for (int r = 0; r < 4; ++r)
                part[(size_t)(tok0 + wave * 32 + mi * 16 + quad * 4 + r) * PROW2
                     + s * 128 + nj * 16 + m16] = acc[mi][nj][r];
}

// ---------------- Stage 2b: reduce 16 contiguous partials, tail GRN, softmax, weighted sum
__global__ __launch_bounds__(256) void vsn_stage2b(
    const unsigned short* __restrict__ stb, const float* __restrict__ part,
    const float* __restrict__ bn1,
    const float* __restrict__ Wn2, const float* __restrict__ bn2,
    const float* __restrict__ Wng, const float* __restrict__ bng,
    const float* __restrict__ bns,
    const float* __restrict__ ngamma, const float* __restrict__ nbeta,
    float* __restrict__ out)
{
    const int t = threadIdx.x;
    const int tok0 = blockIdx.x * 8;
    const int lane = t & 63, wv = t >> 6;

    __shared__ __align__(16) float hw1_s[8][64];
    __shared__ __align__(16) float skw_s[8][64];
    __shared__ __align__(16) float hw2_s[8][64];
    __shared__ float s2_s[8][64];
    __shared__ float w_s[8][64];

    // ---- reduce part[tok][0:16][0:128]; contiguous f4 wave-loads
    #pragma unroll
    for (int tk = 0; tk < 2; ++tk) {
        int tl = wv * 2 + tk;
        const float* pr = part + (size_t)(tok0 + tl) * PROW2
                        + (lane >> 5) * 128 + (lane & 31) * 4;
        float tv[4] = {0.f, 0.f, 0.f, 0.f};
        #pragma unroll
        for (int i = 0; i < 8; ++i) {
            float4 a = *(const float4*)(pr + i * 256);
            tv[0] += a.x; tv[1] += a.y; tv[2] += a.z; tv[3] += a.w;
        }
        #pragma unroll
        for (int c = 0; c < 4; ++c) tv[c] += __shfl_xor(tv[c], 32);
        if (lane < 16) {
            int j0 = lane * 4;
            float4 bb = *(const float4*)(bn1 + j0);
            hw1_s[tl][j0 + 0] = elu_f(tv[0] + bb.x);
            hw1_s[tl][j0 + 1] = elu_f(tv[1] + bb.y);
            hw1_s[tl][j0 + 2] = elu_f(tv[2] + bb.z);
            hw1_s[tl][j0 + 3] = elu_f(tv[3] + bb.w);
        } else if (lane < 32) {
            int j0 = (lane - 16) * 4;
            float4 bb = *(const float4*)(bns + j0);
            skw_s[tl][j0 + 0] = tv[0] + bb.x;
            skw_s[tl][j0 + 1] = tv[1] + bb.y;
            skw_s[tl][j0 + 2] = tv[2] + bb.z;
            skw_s[tl][j0 + 3] = tv[3] + bb.w;
        }
    }
    __syncthreads();

    // ---- hw2 = hw1 @ Wn2 + bn2
    #pragma unroll
    for (int i = 0; i < 2; ++i) {
        int oidx = i * 256 + t;
        int tt = oidx >> 6, jj = oidx & 63;
        float acc = bn2[jj];
        #pragma unroll
        for (int k4 = 0; k4 < 16; ++k4) {
            float4 h = *(const float4*)&hw1_s[tt][k4 * 4];
            acc += h.x * Wn2[(k4*4+0)*64+jj] + h.y * Wn2[(k4*4+1)*64+jj]
                 + h.z * Wn2[(k4*4+2)*64+jj] + h.w * Wn2[(k4*4+3)*64+jj];
        }
        hw2_s[tt][jj] = acc;
    }
    __syncthreads();

    // ---- gw = sigmoid(hw2 @ Wng + bng); s2 = skw + gw*hw2
    #pragma unroll
    for (int i = 0; i < 2; ++i) {
        int oidx = i * 256 + t;
        int tt = oidx >> 6, vv = oidx & 63;
        float acc = bng[vv];
        #pragma unroll
        for (int k4 = 0; k4 < 16; ++k4) {
            float4 h = *(const float4*)&hw2_s[tt][k4 * 4];
            acc += h.x * Wng[(k4*4+0)*64+vv] + h.y * Wng[(k4*4+1)*64+vv]
                 + h.z * Wng[(k4*4+2)*64+vv] + h.w * Wng[(k4*4+3)*64+vv];
        }
        float gw = sigm_f(acc);
        s2_s[tt][vv] = skw_s[tt][vv] + gw * hw2_s[tt][vv];
    }
    __syncthreads();

    // ---- HOISTED stb loads for the weighted sum
    const int vloc = lane >> 3, d8 = (lane & 7) * 8;
    s8v r0[8], r1[8];
    {
        const short* s0 = (const short*)stb + (size_t)(tok0 + wv * 2) * SROW + d8;
        const short* s1 = s0 + SROW;
        #pragma unroll
        for (int vc = 0; vc < 8; ++vc) {
            r0[vc] = *(const s8v*)(s0 + (vc * 8 + vloc) * 64);
            r1[vc] = *(const s8v*)(s1 + (vc * 8 + vloc) * 64);
        }
    }

    // ---- LN over v + softmax; 16 lanes per token
    if (t < 128) {
        int tt = t >> 4, l = t & 15;
        float z[4]; float sum = 0.f, sq = 0.f;
        #pragma unroll
        for (int i = 0; i < 4; ++i) { z[i] = s2_s[tt][l + 16 * i]; sum += z[i]; sq += z[i] * z[i]; }
        #pragma unroll
        for (int m = 1; m < 16; m <<= 1) { sum += __shfl_xor(sum, m); sq += __shfl_xor(sq, m); }
        float mu  = sum * 0.015625f;
        float var = sq * 0.015625f - mu * mu;
        float rs  = rsqrtf(var + LN_EPS);
        float ln[4]; float mx = -1e30f;
        #pragma unroll
        for (int i = 0; i < 4; ++i) {
            ln[i] = (z[i] - mu) * rs * ngamma[l + 16 * i] + nbeta[l + 16 * i];
            mx = fmaxf(mx, ln[i]);
        }
        #pragma unroll
        for (int m = 1; m < 16; m <<= 1) mx = fmaxf(mx, __shfl_xor(mx, m));
        float es = 0.f; float ev[4];
        #pragma unroll
        for (int i = 0; i < 4; ++i) { ev[i] = __expf(ln[i] - mx); es += ev[i]; }
        #pragma unroll
        for (int m = 1; m < 16; m <<= 1) es += __shfl_xor(es, m);
        float inv = 1.f / es;
        #pragma unroll
        for (int i = 0; i < 4; ++i) w_s[tt][l + 16 * i] = ev[i] * inv;
    }
    __syncthreads();

    // ---- weighted sum from the hoisted registers
    {
        float acc0[8], acc1[8];
        #pragma unroll
        for (int j = 0; j < 8; ++j) { acc0[j] = 0.f; acc1[j] = 0.f; }
        #pragma unroll
        for (int vc = 0; vc < 8; ++vc) {
            int v = vc * 8 + vloc;
            float w0 = w_s[wv * 2][v], w1 = w_s[wv * 2 + 1][v];
            #pragma unroll
            for (int j = 0; j < 8; ++j) {
                acc0[j] = fmaf(w0, bf16_to_f((unsigned short)r0[vc][j]), acc0[j]);
                acc1[j] = fmaf(w1, bf16_to_f((unsigned short)r1[vc][j]), acc1[j]);
            }
        }
        #pragma unroll
        for (int m = 8; m <= 32; m <<= 1)
            #pragma unroll
            for (int j = 0; j < 8; ++j) {
                acc0[j] += __shfl_xor(acc0[j], m);
                acc1[j] += __shfl_xor(acc1[j], m);
            }
        if (lane < 8) {
            float* op = out + (size_t)(tok0 + wv * 2) * 64 + lane * 8;
            *(float4*)op       = make_float4(acc0[0], acc0[1], acc0[2], acc0[3]);
            *(float4*)(op + 4) = make_float4(acc0[4], acc0[5], acc0[6], acc0[7]);
            op += 64;
            *(float4*)op       = make_float4(acc1[0], acc1[1], acc1[2], acc1[3]);
            *(float4*)(op + 4) = make_float4(acc1[4], acc1[5], acc1[6], acc1[7]);
        }
    }
}

extern "C" void kernel_launch(void* const* d_in, const int* in_sizes, int n_in,
                              void* d_out, int out_size, void* d_ws, size_t ws_size,
                              hipStream_t stream) {
    const float* x     = (const float*)d_in[0];
    const float* W1    = (const float*)d_in[1];
    const float* b1    = (const float*)d_in[2];
    const float* W2    = (const float*)d_in[3];
    const float* b2    = (const float*)d_in[4];
    const float* Wg    = (const float*)d_in[5];
    const float* bg    = (const float*)d_in[6];
    const float* Wsk   = (const float*)d_in[7];
    const float* bsk   = (const float*)d_in[8];
    const float* gamma = (const float*)d_in[9];
    const float* beta  = (const float*)d_in[10];
    const float* Wn1   = (const float*)d_in[11];
    const float* bn1   = (const float*)d_in[12];
    const float* Wn2   = (const float*)d_in[13];
    const float* bn2   = (const float*)d_in[14];
    const float* Wng   = (const float*)d_in[15];
    const float* bng   = (const float*)d_in[16];
    const float* Wns   = (const float*)d_in[17];
    const float* bns   = (const float*)d_in[18];
    const float* ngam  = (const float*)d_in[19];
    const float* nbet  = (const float*)d_in[20];

    char* ws = (char*)d_ws;
    unsigned short* stb = (unsigned short*)ws;                   // 64 MiB
    short* wct = (short*)(ws + (64u << 20));                     // 1 MiB
    short* w2b = (short*)(ws + (65u << 20));                     // 512 KiB each
    short* wgb = w2b + 262144;
    float* part = (float*)(ws + (66u << 20));                    // 64 MiB (8192 x 2048)
    float* outp = (float*)d_out;

    vsn_prepack<<<dim3(192), 256, 0, stream>>>(W2, Wg, Wn1, Wns, w2b, wgb, wct);
    vsn_stage1<<<dim3(NTOK / 128, 16), 256, 0, stream>>>(
        x, W1, b1, w2b, wgb, b2, bg, Wsk, bsk, gamma, beta, stb);
    vsn_stage2a<<<dim3(NTOK / 128, KSPLIT), 256, 0, stream>>>(stb, wct, part);
    vsn_stage2b<<<dim3(NTOK / 8), 256, 0, stream>>>(
        stb, part, bn1, Wn2, bn2, Wng, bng, bns, ngam, nbet, outp);
}

// Round 16
// 186.030 us; speedup vs baseline: 1.2935x; 1.0859x over previous
//
#include <hip/hip_runtime.h>
#include <hip/hip_bf16.h>
#include <math.h>

#define NV 64
#define ND 64
#define NTOK 8192
#define LN_EPS 1e-5f
#define SROW 4096
#define WROW 4096
#define KSPLIT 8
#define KR2 (4096 / KSPLIT)     // 512
#define BK 64
#define PROW2 (KSPLIT * 128)    // 1024

typedef __attribute__((ext_vector_type(8))) short s8v;    // 8 bf16 = 4 VGPR
typedef __attribute__((ext_vector_type(4))) float f4v;    // MFMA C/D
typedef __attribute__((ext_vector_type(4))) int   i4v;

__device__ __forceinline__ float sigm_f(float x) {
    return __builtin_amdgcn_rcpf(1.f + __expf(-x));
}
__device__ __forceinline__ float elu_f(float x)  { return x > 0.f ? x : (__expf(x) - 1.f); }

__device__ __forceinline__ float bf16_to_f(unsigned short s) {
    union { unsigned int u; float f; } c; c.u = ((unsigned int)s) << 16;
    return c.f;
}
__device__ __forceinline__ unsigned short bf16_rn(float f) {
    union { float f; unsigned int u; } c; c.f = f;
    return (unsigned short)((c.u + 0x8000u) >> 16);
}

// ---------------- Prepack: weight transposes via LDS tiles (coalesced R+W)
__global__ __launch_bounds__(256) void vsn_prepack(
    const float* __restrict__ W2, const float* __restrict__ Wg,
    const float* __restrict__ Wn1, const float* __restrict__ Wns,
    short* __restrict__ w2b, short* __restrict__ wgb,
    short* __restrict__ wct)
{
    __shared__ float T[64][65];
    const int b = blockIdx.x, t = threadIdx.x;

    if (b < 64) {
        const float* src = W2 + (size_t)b * 4096;
        short* dst = w2b + (size_t)b * 4096;
        #pragma unroll
        for (int pass = 0; pass < 2; ++pass) {
            #pragma unroll
            for (int i = 0; i < 16; ++i) {
                int id = i * 256 + t;
                T[id & 63][id >> 6] = src[id];
            }
            __syncthreads();
            #pragma unroll
            for (int i = 0; i < 16; ++i) {
                int id = i * 256 + t;
                dst[id] = (short)bf16_rn(T[id >> 6][id & 63]);
            }
            __syncthreads();
            src = Wg + (size_t)b * 4096;
            dst = wgb + (size_t)b * 4096;
        }
    } else {
        int tb = b - 64;
        int half = tb >> 6, kt = tb & 63;
        const float* src = (half == 0 ? Wn1 : Wns) + (size_t)(kt * 64) * 64;
        #pragma unroll
        for (int i = 0; i < 16; ++i) {
            int id = i * 256 + t;
            T[id & 63][id >> 6] = src[id];
        }
        __syncthreads();
        #pragma unroll
        for (int i = 0; i < 16; ++i) {
            int id = i * 256 + t;
            int n = id >> 6, r = id & 63;
            wct[(size_t)(half * 64 + n) * WROW + kt * 64 + r] = (short)bf16_rn(T[n][r]);
        }
    }
}

// ---------------- Stage 1: per-variable GRN + LN via bf16 MFMA -> stacked bf16
// [R13/R15 verified @60-61us; sigm via fast rcp]
__global__ __launch_bounds__(256) void vsn_stage1(
    const float* __restrict__ x,
    const float* __restrict__ W1, const float* __restrict__ b1,
    const short* __restrict__ w2b, const short* __restrict__ wgb,
    const float* __restrict__ b2, const float* __restrict__ bg,
    const float* __restrict__ Wsk, const float* __restrict__ bsk,
    const float* __restrict__ gamma, const float* __restrict__ beta,
    unsigned short* __restrict__ stb)
{
    const int t = threadIdx.x;
    const int wave = t >> 6, lane = t & 63;
    const int m16 = lane & 15, quad = lane >> 4;
    const int v = blockIdx.y * 4 + wave;

    __shared__ float xs[4][32];
    __shared__ __align__(16) unsigned short h2s[4][32][72];

    float w1k[2][8], b1k[2][8];
    #pragma unroll
    for (int kt = 0; kt < 2; ++kt) {
        *(float4*)&w1k[kt][0] = *(const float4*)(W1 + v * 64 + kt * 32 + quad * 8);
        *(float4*)&w1k[kt][4] = *(const float4*)(W1 + v * 64 + kt * 32 + quad * 8 + 4);
        *(float4*)&b1k[kt][0] = *(const float4*)(b1 + v * 64 + kt * 32 + quad * 8);
        *(float4*)&b1k[kt][4] = *(const float4*)(b1 + v * 64 + kt * 32 + quad * 8 + 4);
    }
    float b2d[4], bgd[4], wskd[4], bskd[4], gamd[4], betd[4];
    #pragma unroll
    for (int ni = 0; ni < 4; ++ni) {
        int d = v * 64 + ni * 16 + m16;
        b2d[ni] = b2[d]; bgd[ni] = bg[d]; wskd[ni] = Wsk[d]; bskd[ni] = bsk[d];
        gamd[ni] = gamma[d]; betd[ni] = beta[d];
    }
    const size_t wb = (size_t)v * 4096;

    for (int tt4 = 0; tt4 < 4; ++tt4) {
        const int tile0 = blockIdx.x * 128 + tt4 * 32;

        if (lane < 32) xs[wave][lane] = x[(size_t)(tile0 + lane) * NV + v];

        s8v a[2][2];
        #pragma unroll
        for (int kt = 0; kt < 2; ++kt)
            #pragma unroll
            for (int mi = 0; mi < 2; ++mi) {
                float xv = xs[wave][mi * 16 + m16];
                float h[8];
                #pragma unroll
                for (int j = 0; j < 8; ++j) h[j] = elu_f(fmaf(xv, w1k[kt][j], b1k[kt][j]));
                i4v av;
                #pragma unroll
                for (int p = 0; p < 4; ++p) {
                    unsigned int u0 = __float_as_uint(h[2 * p]);
                    unsigned int u1 = __float_as_uint(h[2 * p + 1]);
                    av[p] = (int)((u1 & 0xffff0000u) | (u0 >> 16));
                }
                a[mi][kt] = *(s8v*)&av;
            }

        f4v hacc[2][4];
        #pragma unroll
        for (int mi = 0; mi < 2; ++mi)
            #pragma unroll
            for (int ni = 0; ni < 4; ++ni) hacc[mi][ni] = (f4v){0.f, 0.f, 0.f, 0.f};
        #pragma unroll
        for (int ni = 0; ni < 4; ++ni)
            #pragma unroll
            for (int kt = 0; kt < 2; ++kt) {
                s8v bh = *(const s8v*)(w2b + wb + (size_t)(ni * 16 + m16) * 64 + kt * 32 + quad * 8);
                #pragma unroll
                for (int mi = 0; mi < 2; ++mi)
                    hacc[mi][ni] = __builtin_amdgcn_mfma_f32_16x16x32_bf16(a[mi][kt], bh, hacc[mi][ni], 0, 0, 0);
            }
        #pragma unroll
        for (int mi = 0; mi < 2; ++mi)
            #pragma unroll
            for (int ni = 0; ni < 4; ++ni)
                #pragma unroll
                for (int r = 0; r < 4; ++r) hacc[mi][ni][r] += b2d[ni];

        #pragma unroll
        for (int mi = 0; mi < 2; ++mi)
            #pragma unroll
            for (int ni = 0; ni < 4; ++ni)
                #pragma unroll
                for (int r = 0; r < 4; ++r)
                    h2s[wave][mi * 16 + quad * 4 + r][ni * 16 + m16] =
                        (unsigned short)(__float_as_uint(hacc[mi][ni][r]) >> 16);

        s8v c[2][2];
        #pragma unroll
        for (int mi = 0; mi < 2; ++mi)
            #pragma unroll
            for (int kt = 0; kt < 2; ++kt)
                c[mi][kt] = *(const s8v*)&h2s[wave][mi * 16 + m16][kt * 32 + quad * 8];

        f4v gacc[2][4];
        #pragma unroll
        for (int mi = 0; mi < 2; ++mi)
            #pragma unroll
            for (int ni = 0; ni < 4; ++ni) gacc[mi][ni] = (f4v){0.f, 0.f, 0.f, 0.f};
        #pragma unroll
        for (int ni = 0; ni < 4; ++ni)
            #pragma unroll
            for (int kt = 0; kt < 2; ++kt) {
                s8v bh = *(const s8v*)(wgb + wb + (size_t)(ni * 16 + m16) * 64 + kt * 32 + quad * 8);
                #pragma unroll
                for (int mi = 0; mi < 2; ++mi)
                    gacc[mi][ni] = __builtin_amdgcn_mfma_f32_16x16x32_bf16(c[mi][kt], bh, gacc[mi][ni], 0, 0, 0);
            }

        {
            float xtok[2][4];
            #pragma unroll
            for (int mi = 0; mi < 2; ++mi)
                #pragma unroll
                for (int r = 0; r < 4; ++r) xtok[mi][r] = xs[wave][mi * 16 + quad * 4 + r];
            #pragma unroll
            for (int mi = 0; mi < 2; ++mi)
                #pragma unroll
                for (int ni = 0; ni < 4; ++ni)
                    #pragma unroll
                    for (int r = 0; r < 4; ++r) {
                        float g = sigm_f(gacc[mi][ni][r] + bgd[ni]);
                        gacc[mi][ni][r] = fmaf(xtok[mi][r], wskd[ni], bskd[ni]) + g * hacc[mi][ni][r];
                    }
        }

        #pragma unroll
        for (int mi = 0; mi < 2; ++mi)
            #pragma unroll
            for (int r = 0; r < 4; ++r) {
                float s0 = gacc[mi][0][r], s1 = gacc[mi][1][r], s2 = gacc[mi][2][r], s3 = gacc[mi][3][r];
                float sum = s0 + s1 + s2 + s3;
                float sq  = s0 * s0 + s1 * s1 + s2 * s2 + s3 * s3;
                #pragma unroll
                for (int m = 1; m < 16; m <<= 1) { sum += __shfl_xor(sum, m); sq += __shfl_xor(sq, m); }
                float mu  = sum * 0.015625f;
                float var = sq * 0.015625f - mu * mu;
                float rs  = __builtin_amdgcn_rsqf(var + LN_EPS);
                size_t base = (size_t)(tile0 + mi * 16 + quad * 4 + r) * SROW + (size_t)v * 64 + m16;
                #pragma unroll
                for (int ni = 0; ni < 4; ++ni)
                    stb[base + ni * 16] =
                        bf16_rn((gacc[mi][ni][r] - mu) * rs * gamd[ni] + betd[ni]);
            }
    }
}

// ---------------- Stage 2a: LDS-tiled GEMM. KSPLIT=8, 512 thr (8 waves),
// tile M=128 x N=128, BK=64. Wave: mw = w&3 (32 rows), nw = w>>2 (64 cols).
__global__ __launch_bounds__(512) void vsn_stage2a(
    const unsigned short* __restrict__ stb,   // [8192][SROW]
    const short* __restrict__ wct,            // [128][WROW]
    float* __restrict__ part)                 // [8192][PROW2]
{
    const int t = threadIdx.x;
    const int wave = t >> 6, lane = t & 63;
    const int m16 = lane & 15, quad = lane >> 4;
    const int mw = wave & 3, nw = wave >> 2;
    const int tok0 = blockIdx.x * 128;
    const int s = blockIdx.y;
    const int k0 = s * KR2;

    __shared__ __align__(16) unsigned short Al[128][72];   // pad 72: 2-way banks (free)
    __shared__ __align__(16) unsigned short Bl[128][72];

    const int srow = t >> 3;            // 0..63 (+64 for q=1)
    const int scol = (t & 7) * 8;       // shorts (16B chunk)
    const short* A = (const short*)stb;

    f4v acc[2][4];
    #pragma unroll
    for (int mi = 0; mi < 2; ++mi)
        #pragma unroll
        for (int nj = 0; nj < 4; ++nj) acc[mi][nj] = (f4v){0.f, 0.f, 0.f, 0.f};

    // prefetch chunk 0
    s8v pa[2], pb[2];
    #pragma unroll
    for (int q = 0; q < 2; ++q) {
        int row = srow + q * 64;
        pa[q] = *(const s8v*)(A + (size_t)(tok0 + row) * SROW + k0 + scol);
        pb[q] = *(const s8v*)(wct + (size_t)row * WROW + k0 + scol);
    }

    for (int kc = 0; kc < KR2 / BK; ++kc) {
        if (kc > 0) __syncthreads();
        #pragma unroll
        for (int q = 0; q < 2; ++q) {
            int row = srow + q * 64;
            *(s8v*)&Al[row][scol] = pa[q];
            *(s8v*)&Bl[row][scol] = pb[q];
        }
        __syncthreads();
        if (kc + 1 < KR2 / BK) {
            int kn = k0 + (kc + 1) * BK;
            #pragma unroll
            for (int q = 0; q < 2; ++q) {
                int row = srow + q * 64;
                pa[q] = *(const s8v*)(A + (size_t)(tok0 + row) * SROW + kn + scol);
                pb[q] = *(const s8v*)(wct + (size_t)row * WROW + kn + scol);
            }
        }
        #pragma unroll
        for (int ks = 0; ks < 2; ++ks) {
            s8v af[2], bf[4];
            #pragma unroll
            for (int mi = 0; mi < 2; ++mi)
                af[mi] = *(const s8v*)&Al[mw * 32 + mi * 16 + m16][ks * 32 + quad * 8];
            #pragma unroll
            for (int nj = 0; nj < 4; ++nj)
                bf[nj] = *(const s8v*)&Bl[nw * 64 + nj * 16 + m16][ks * 32 + quad * 8];
            #pragma unroll
            for (int mi = 0; mi < 2; ++mi)
                #pragma unroll
                for (int nj = 0; nj < 4; ++nj)
                    acc[mi][nj] = __builtin_amdgcn_mfma_f32_16x16x32_bf16(af[mi], bf[nj], acc[mi][nj], 0, 0, 0);
        }
    }

    #pragma unroll
    for (int mi = 0; mi < 2; ++mi)
        #pragma unroll
        for (int nj = 0; nj < 4; ++nj)
            #pragma unroll
            for (int r = 0; r < 4; ++r)
                part[(size_t)(tok0 + mw * 32 + mi * 16 + quad * 4 + r) * PROW2
                     + s * 128 + nw * 64 + nj * 16 + m16] = acc[mi][nj][r];
}

// ---------------- Stage 2b: reduce 8 contiguous partials, tail GRN, softmax, weighted sum
__global__ __launch_bounds__(256) void vsn_stage2b(
    const unsigned short* __restrict__ stb, const float* __restrict__ part,
    const float* __restrict__ bn1,
    const float* __restrict__ Wn2, const float* __restrict__ bn2,
    const float* __restrict__ Wng, const float* __restrict__ bng,
    const float* __restrict__ bns,
    const float* __restrict__ ngamma, const float* __restrict__ nbeta,
    float* __restrict__ out)
{
    const int t = threadIdx.x;
    const int tok0 = blockIdx.x * 8;
    const int lane = t & 63, wv = t >> 6;

    __shared__ __align__(16) float hw1_s[8][64];
    __shared__ __align__(16) float skw_s[8][64];
    __shared__ __align__(16) float hw2_s[8][64];
    __shared__ float s2_s[8][64];
    __shared__ float w_s[8][64];

    // ---- reduce part[tok][0:8][0:128]; contiguous f4 wave-loads
    #pragma unroll
    for (int tk = 0; tk < 2; ++tk) {
        int tl = wv * 2 + tk;
        const float* pr = part + (size_t)(tok0 + tl) * PROW2
                        + (lane >> 5) * 128 + (lane & 31) * 4;
        float tv[4] = {0.f, 0.f, 0.f, 0.f};
        #pragma unroll
        for (int i = 0; i < 4; ++i) {
            float4 a = *(const float4*)(pr + i * 256);
            tv[0] += a.x; tv[1] += a.y; tv[2] += a.z; tv[3] += a.w;
        }
        #pragma unroll
        for (int c = 0; c < 4; ++c) tv[c] += __shfl_xor(tv[c], 32);
        if (lane < 16) {
            int j0 = lane * 4;
            float4 bb = *(const float4*)(bn1 + j0);
            hw1_s[tl][j0 + 0] = elu_f(tv[0] + bb.x);
            hw1_s[tl][j0 + 1] = elu_f(tv[1] + bb.y);
            hw1_s[tl][j0 + 2] = elu_f(tv[2] + bb.z);
            hw1_s[tl][j0 + 3] = elu_f(tv[3] + bb.w);
        } else if (lane < 32) {
            int j0 = (lane - 16) * 4;
            float4 bb = *(const float4*)(bns + j0);
            skw_s[tl][j0 + 0] = tv[0] + bb.x;
            skw_s[tl][j0 + 1] = tv[1] + bb.y;
            skw_s[tl][j0 + 2] = tv[2] + bb.z;
            skw_s[tl][j0 + 3] = tv[3] + bb.w;
        }
    }
    __syncthreads();

    // ---- hw2 = hw1 @ Wn2 + bn2
    #pragma unroll
    for (int i = 0; i < 2; ++i) {
        int oidx = i * 256 + t;
        int tt = oidx >> 6, jj = oidx & 63;
        float acc = bn2[jj];
        #pragma unroll
        for (int k4 = 0; k4 < 16; ++k4) {
            float4 h = *(const float4*)&hw1_s[tt][k4 * 4];
            acc += h.x * Wn2[(k4*4+0)*64+jj] + h.y * Wn2[(k4*4+1)*64+jj]
                 + h.z * Wn2[(k4*4+2)*64+jj] + h.w * Wn2[(k4*4+3)*64+jj];
        }
        hw2_s[tt][jj] = acc;
    }
    __syncthreads();

    // ---- gw = sigmoid(hw2 @ Wng + bng); s2 = skw + gw*hw2
    #pragma unroll
    for (int i = 0; i < 2; ++i) {
        int oidx = i * 256 + t;
        int tt = oidx >> 6, vv = oidx & 63;
        float acc = bng[vv];
        #pragma unroll
        for (int k4 = 0; k4 < 16; ++k4) {
            float4 h = *(const float4*)&hw2_s[tt][k4 * 4];
            acc += h.x * Wng[(k4*4+0)*64+vv] + h.y * Wng[(k4*4+1)*64+vv]
                 + h.z * Wng[(k4*4+2)*64+vv] + h.w * Wng[(k4*4+3)*64+vv];
        }
        float gw = sigm_f(acc);
        s2_s[tt][vv] = skw_s[tt][vv] + gw * hw2_s[tt][vv];
    }
    __syncthreads();

    // ---- HOISTED stb loads for the weighted sum
    const int vloc = lane >> 3, d8 = (lane & 7) * 8;
    s8v r0[8], r1[8];
    {
        const short* s0 = (const short*)stb + (size_t)(tok0 + wv * 2) * SROW + d8;
        const short* s1 = s0 + SROW;
        #pragma unroll
        for (int vc = 0; vc < 8; ++vc) {
            r0[vc] = *(const s8v*)(s0 + (vc * 8 + vloc) * 64);
            r1[vc] = *(const s8v*)(s1 + (vc * 8 + vloc) * 64);
        }
    }

    // ---- LN over v + softmax; 16 lanes per token
    if (t < 128) {
        int tt = t >> 4, l = t & 15;
        float z[4]; float sum = 0.f, sq = 0.f;
        #pragma unroll
        for (int i = 0; i < 4; ++i) { z[i] = s2_s[tt][l + 16 * i]; sum += z[i]; sq += z[i] * z[i]; }
        #pragma unroll
        for (int m = 1; m < 16; m <<= 1) { sum += __shfl_xor(sum, m); sq += __shfl_xor(sq, m); }
        float mu  = sum * 0.015625f;
        float var = sq * 0.015625f - mu * mu;
        float rs  = __builtin_amdgcn_rsqf(var + LN_EPS);
        float ln[4]; float mx = -1e30f;
        #pragma unroll
        for (int i = 0; i < 4; ++i) {
            ln[i] = (z[i] - mu) * rs * ngamma[l + 16 * i] + nbeta[l + 16 * i];
            mx = fmaxf(mx, ln[i]);
        }
        #pragma unroll
        for (int m = 1; m < 16; m <<= 1) mx = fmaxf(mx, __shfl_xor(mx, m));
        float es = 0.f; float ev[4];
        #pragma unroll
        for (int i = 0; i < 4; ++i) { ev[i] = __expf(ln[i] - mx); es += ev[i]; }
        #pragma unroll
        for (int m = 1; m < 16; m <<= 1) es += __shfl_xor(es, m);
        float inv = __builtin_amdgcn_rcpf(es);
        #pragma unroll
        for (int i = 0; i < 4; ++i) w_s[tt][l + 16 * i] = ev[i] * inv;
    }
    __syncthreads();

    // ---- weighted sum from the hoisted registers
    {
        float acc0[8], acc1[8];
        #pragma unroll
        for (int j = 0; j < 8; ++j) { acc0[j] = 0.f; acc1[j] = 0.f; }
        #pragma unroll
        for (int vc = 0; vc < 8; ++vc) {
            int v = vc * 8 + vloc;
            float w0 = w_s[wv * 2][v], w1 = w_s[wv * 2 + 1][v];
            #pragma unroll
            for (int j = 0; j < 8; ++j) {
                acc0[j] = fmaf(w0, bf16_to_f((unsigned short)r0[vc][j]), acc0[j]);
                acc1[j] = fmaf(w1, bf16_to_f((unsigned short)r1[vc][j]), acc1[j]);
            }
        }
        #pragma unroll
        for (int m = 8; m <= 32; m <<= 1)
            #pragma unroll
            for (int j = 0; j < 8; ++j) {
                acc0[j] += __shfl_xor(acc0[j], m);
                acc1[j] += __shfl_xor(acc1[j], m);
            }
        if (lane < 8) {
            float* op = out + (size_t)(tok0 + wv * 2) * 64 + lane * 8;
            *(float4*)op       = make_float4(acc0[0], acc0[1], acc0[2], acc0[3]);
            *(float4*)(op + 4) = make_float4(acc0[4], acc0[5], acc0[6], acc0[7]);
            op += 64;
            *(float4*)op       = make_float4(acc1[0], acc1[1], acc1[2], acc1[3]);
            *(float4*)(op + 4) = make_float4(acc1[4], acc1[5], acc1[6], acc1[7]);
        }
    }
}

extern "C" void kernel_launch(void* const* d_in, const int* in_sizes, int n_in,
                              void* d_out, int out_size, void* d_ws, size_t ws_size,
                              hipStream_t stream) {
    const float* x     = (const float*)d_in[0];
    const float* W1    = (const float*)d_in[1];
    const float* b1    = (const float*)d_in[2];
    const float* W2    = (const float*)d_in[3];
    const float* b2    = (const float*)d_in[4];
    const float* Wg    = (const float*)d_in[5];
    const float* bg    = (const float*)d_in[6];
    const float* Wsk   = (const float*)d_in[7];
    const float* bsk   = (const float*)d_in[8];
    const float* gamma = (const float*)d_in[9];
    const float* beta  = (const float*)d_in[10];
    const float* Wn1   = (const float*)d_in[11];
    const float* bn1   = (const float*)d_in[12];
    const float* Wn2   = (const float*)d_in[13];
    const float* bn2   = (const float*)d_in[14];
    const float* Wng   = (const float*)d_in[15];
    const float* bng   = (const float*)d_in[16];
    const float* Wns   = (const float*)d_in[17];
    const float* bns   = (const float*)d_in[18];
    const float* ngam  = (const float*)d_in[19];
    const float* nbet  = (const float*)d_in[20];

    char* ws = (char*)d_ws;
    unsigned short* stb = (unsigned short*)ws;                   // 64 MiB
    short* wct = (short*)(ws + (64u << 20));                     // 1 MiB
    short* w2b = (short*)(ws + (65u << 20));                     // 512 KiB each
    short* wgb = w2b + 262144;
    float* part = (float*)(ws + (66u << 20));                    // 32 MiB (8192 x 1024)
    float* outp = (float*)d_out;

    vsn_prepack<<<dim3(192), 256, 0, stream>>>(W2, Wg, Wn1, Wns, w2b, wgb, wct);
    vsn_stage1<<<dim3(NTOK / 128, 16), 256, 0, stream>>>(
        x, W1, b1, w2b, wgb, b2, bg, Wsk, bsk, gamma, beta, stb);
    vsn_stage2a<<<dim3(NTOK / 128, KSPLIT), 512, 0, stream>>>(stb, wct, part);
    vsn_stage2b<<<dim3(NTOK / 8), 256, 0, stream>>>(
        stb, part, bn1, Wn2, bn2, Wng, bng, bns, ngam, nbet, outp);
}